// Round 19
// baseline (224.606 us; speedup 1.0000x reference)
//
#include <hip/hip_runtime.h>
#include <math.h>

#define Bb   2
#define Rr   384
#define CMd  384
#define CZ   128
#define Hh   12
#define DHd  32

#define WL           1.7320508075688772f   // sqrt(3)
#define WC           4.242640687119285f    // sqrt(18) = (2/(9*4))^-0.5
#define INV_SQRT_DH  0.17677669529663687f  // 32^-0.5

#define SZ_R   (Bb*Hh*Rr*DHd)      // 294912
#define SZ_T   (Bb*Hh*Rr*12)      // 110592
#define SZ_S   (Bb*Hh*Rr)         // 9216
#define SZ_A   ((long)Bb*Hh*Rr*Rr) // 3538944
#define SZ_O   (Bb*Rr*Hh*DHd)     // 294912

// ---------------------------------------------------------------- K1a: projection GEMM (R8 exact)
__global__ __launch_bounds__(64) void k_projgemm(
    const float* __restrict__ sing, const float* __restrict__ Wqkv,
    const float* __restrict__ Wqk, float* __restrict__ pbuf)
{
  const int t = threadIdx.x;
  const int m0 = blockIdx.x * 32;
  const int n0 = blockIdx.y * 32;
  const int ks = blockIdx.z;
  const int tx = t & 7, ty = t >> 3;
  __shared__ float As[32][36];
  __shared__ float Bs[32][36];
  float acc[4][4] = {};

  for (int kc = ks*192; kc < ks*192 + 192; kc += 32) {
    #pragma unroll
    for (int i = 0; i < 4; ++i) {
      int s = t + 64*i;
      int row = s >> 3, k4 = (s & 7) << 2;
      float4 v = *(const float4*)(sing + (long)(m0 + row)*384 + kc + k4);
      As[k4  ][row] = v.x; As[k4+1][row] = v.y;
      As[k4+2][row] = v.z; As[k4+3][row] = v.w;
    }
    #pragma unroll
    for (int i = 0; i < 4; ++i) {
      int s = t + 64*i;
      int k = s >> 3, c4 = (s & 7) << 2;
      const float* srcB = (n0 < 1152)
          ? Wqkv + (long)(kc + k)*1152 + n0 + c4
          : Wqk  + (long)(kc + k)*288 + (n0 - 1152) + c4;
      float4 w = *(const float4*)srcB;
      Bs[k][c4] = w.x; Bs[k][c4+1] = w.y; Bs[k][c4+2] = w.z; Bs[k][c4+3] = w.w;
    }
    __syncthreads();
    #pragma unroll
    for (int k = 0; k < 32; ++k) {
      float4 a = *(const float4*)&As[k][ty*4];
      float4 b = *(const float4*)&Bs[k][tx*4];
      acc[0][0] += a.x*b.x; acc[0][1] += a.x*b.y; acc[0][2] += a.x*b.z; acc[0][3] += a.x*b.w;
      acc[1][0] += a.y*b.x; acc[1][1] += a.y*b.y; acc[1][2] += a.y*b.z; acc[1][3] += a.y*b.w;
      acc[2][0] += a.z*b.x; acc[2][1] += a.z*b.y; acc[2][2] += a.z*b.z; acc[2][3] += a.z*b.w;
      acc[3][0] += a.w*b.x; acc[3][1] += a.w*b.y; acc[3][2] += a.w*b.z; acc[3][3] += a.w*b.w;
    }
    __syncthreads();
  }
  float* pd = pbuf + (long)ks * (768*1440);
  #pragma unroll
  for (int i = 0; i < 4; ++i)
    *(float4*)&pd[(long)(m0 + ty*4 + i)*1440 + n0 + tx*4] =
        make_float4(acc[i][0], acc[i][1], acc[i][2], acc[i][3]);
}

// ---------------------------------------------------------------- K1a2: reduce partials + scatter (R8 exact)
__global__ __launch_bounds__(256) void k_scatter(
    const float* __restrict__ pbuf,
    float* __restrict__ rq, float* __restrict__ rk, float* __restrict__ rv,
    float* __restrict__ gbuf)
{
  const int idx = blockIdx.x*256 + threadIdx.x;   // over 276480 float4
  const int row = idx / 360;
  const int n   = (idx - row*360) * 4;
  float4 a = ((const float4*)pbuf)[idx];
  float4 b = ((const float4*)(pbuf + (long)768*1440))[idx];
  float v[4] = {a.x + b.x, a.y + b.y, a.z + b.z, a.w + b.w};
  const int bb = row / Rr, rr = row - bb*Rr;
  #pragma unroll
  for (int j = 0; j < 4; ++j) {
    int nj = n + j;
    if (nj < 1152) {
      int d = nj/36, rem = nj - d*36, wh = rem/12, h = rem - wh*12;
      float* dst = (wh == 0) ? rq : (wh == 1) ? rk : rv;
      dst[(((long)bb*Hh + h)*Rr + rr)*DHd + d] = v[j];
    } else {
      gbuf[(long)row*288 + nj - 1152] = v[j];
    }
  }
}

// ---------------------------------------------------------------- K1b: frame transform (R8 exact)
__global__ __launch_bounds__(256) void k_frame(
    const float* __restrict__ gbuf, const float* __restrict__ bbr,
    const float* __restrict__ bbt,
    float* __restrict__ TqF, float* __restrict__ TkF,
    float* __restrict__ Qsq, float* __restrict__ Ksq)
{
  const int idx = blockIdx.x*256 + threadIdx.x;   // 768*24 exact
  const int row = idx / 24, q = idx - row*24;
  const int h = q >> 1, s2 = q & 1;
  const float* gp = gbuf + (long)row*288 + h*24 + s2*12;
  float rot[9], tr[3];
  #pragma unroll
  for (int a = 0; a < 9; ++a) rot[a] = bbr[(long)row*9 + a];
  #pragma unroll
  for (int a = 0; a < 3; ++a) tr[a] = bbt[(long)row*3 + a];
  const int b = row / Rr, r = row - b*Rr;
  float* T = s2 ? TkF : TqF;
  const long tb = (((long)b*Hh + h)*Rr + r)*12;
  float v[12]; float ss = 0.f;
  #pragma unroll
  for (int p = 0; p < 4; ++p)
    #pragma unroll
    for (int k2 = 0; k2 < 3; ++k2) {
      float x = gp[p*3+0]*rot[k2] + gp[p*3+1]*rot[3+k2] + gp[p*3+2]*rot[6+k2] + tr[k2];
      v[p*3+k2] = x; ss += x*x;
    }
  *(float4*)(T + tb)     = make_float4(v[0], v[1], v[2],  v[3]);
  *(float4*)(T + tb + 4) = make_float4(v[4], v[5], v[6],  v[7]);
  *(float4*)(T + tb + 8) = make_float4(v[8], v[9], v[10], v[11]);
  (s2 ? Ksq : Qsq)[((long)b*Hh + h)*Rr + r] = ss;
}

// ---------------------------------------------------------------- K_pscore: fused pair-bias + logits + softmax
// one block per (b,i). Phase A = R15-pbias pattern into LDS; Phase B = logit pass;
// Phase C = wave softmax, registers -> global attn (single coalesced write).
__global__ __launch_bounds__(256) void k_pscore(
    const float* __restrict__ pair, const float* __restrict__ Wfc1,
    const float* __restrict__ bfc1,
    const float* __restrict__ rq, const float* __restrict__ rk,
    const float* __restrict__ TqF, const float* __restrict__ TkF,
    const float* __restrict__ Qsq, const float* __restrict__ Ksq,
    const float* __restrict__ gamma, float* __restrict__ attn)
{
  const int t = threadIdx.x;
  const int bi = blockIdx.x;
  const int b = bi / Rr;
  const int i = bi - b*Rr;
  __shared__ __align__(16) float w_t[12*128];    // [h][c] transposed W_fc1
  __shared__ float attn_l[12][388];              // 18.6 KB
  __shared__ __align__(16) float rq_l[12][32];
  __shared__ float tq_l[12][12];
  __shared__ float bias_l[12], qs_l[12];

  for (int s = t; s < 1536; s += 256) {
    int h = s >> 7, c = s & 127;
    w_t[s] = Wfc1[c*12 + h];
  }
  for (int s = t; s < 384; s += 256) {
    int h = s >> 5, d = s & 31;
    rq_l[h][d] = rq[(((long)b*Hh + h)*Rr + i)*DHd + d];
  }
  if (t < 144) tq_l[t/12][t%12] = TqF[(((long)b*Hh + t/12)*Rr + i)*12 + t%12];
  if (t < 12) { bias_l[t] = bfc1[t]; qs_l[t] = Qsq[((long)b*Hh + t)*Rr + i]; }
  const float head_w = log1pf(__expf(gamma[0])) * (WC * 0.5f);
  __syncthreads();

  // ---- Phase A: pair bias (R15 pattern: su-sliced row, w_t b128 broadcasts, shfl reduce)
  {
    const int su = t & 7, rg = t >> 3;           // rg in [0,32)
    const float4* pr = (const float4*)(pair + (long)bi * Rr * CZ);
    for (int k = 0; k < 12; ++k) {
      const int j = k*32 + rg;
      float acc[12] = {};
      #pragma unroll
      for (int cc = 0; cc < 4; ++cc) {
        const int f = su + 8*cc;
        float4 p = pr[(long)j*32 + f];
        #pragma unroll
        for (int h = 0; h < 12; ++h) {
          float4 wv = *(const float4*)&w_t[h*128 + f*4];
          acc[h] += p.x*wv.x + p.y*wv.y + p.z*wv.z + p.w*wv.w;
        }
      }
      #pragma unroll
      for (int h = 0; h < 12; ++h) {
        float v = acc[h];
        v += __shfl_xor(v, 1, 64);
        v += __shfl_xor(v, 2, 64);
        v += __shfl_xor(v, 4, 64);
        if (su == 0) attn_l[h][j] = v + bias_l[h];
      }
    }
  }
  __syncthreads();

  // ---- Phase B: + scalar dot + point-distance term (L2-resident rk/TkF/Ksq)
  for (int k = 0; k < 18; ++k) {
    int tid = t + 256*k;                         // 4608 = 12*384
    int h = tid / 384, j = tid - h*384;
    const long rbase = ((long)b*Hh + h)*Rr + j;
    const float4* kp = (const float4*)(rk + rbase*DHd);
    float dt = 0.f;
    #pragma unroll
    for (int q4 = 0; q4 < 8; ++q4) {
      float4 v = kp[q4];
      dt += rq_l[h][q4*4]*v.x + rq_l[h][q4*4+1]*v.y + rq_l[h][q4*4+2]*v.z + rq_l[h][q4*4+3]*v.w;
    }
    const float4* tk = (const float4*)(TkF + rbase*12);
    float4 ta = tk[0], tb2 = tk[1], tc = tk[2];
    float pt = tq_l[h][0]*ta.x + tq_l[h][1]*ta.y + tq_l[h][2]*ta.z + tq_l[h][3]*ta.w
             + tq_l[h][4]*tb2.x + tq_l[h][5]*tb2.y + tq_l[h][6]*tb2.z + tq_l[h][7]*tb2.w
             + tq_l[h][8]*tc.x + tq_l[h][9]*tc.y + tq_l[h][10]*tc.z + tq_l[h][11]*tc.w;
    float sq = qs_l[h] + Ksq[rbase] - 2.f*pt;
    attn_l[h][j] = WL * (attn_l[h][j] + dt*INV_SQRT_DH + head_w*sq);
  }
  __syncthreads();

  // ---- Phase C: softmax per head row (wave w handles h = w, w+4, w+8); write global
  {
    const int w = t >> 6, lane = t & 63;
    #pragma unroll
    for (int r = 0; r < 3; ++r) {
      const int h = w + 4*r;
      float x[6];
      #pragma unroll
      for (int k = 0; k < 6; ++k) x[k] = attn_l[h][lane + 64*k];
      float m = x[0];
      #pragma unroll
      for (int k = 1; k < 6; ++k) m = fmaxf(m, x[k]);
      #pragma unroll
      for (int s = 32; s; s >>= 1) m = fmaxf(m, __shfl_xor(m, s, 64));
      float sum = 0.f;
      #pragma unroll
      for (int k = 0; k < 6; ++k) { x[k] = __expf(x[k] - m); sum += x[k]; }
      #pragma unroll
      for (int s = 32; s; s >>= 1) sum += __shfl_xor(sum, s, 64);
      const float inv = 1.f / sum;
      float* arow = attn + (((long)b*Hh + h)*Rr + i)*Rr;
      #pragma unroll
      for (int k = 0; k < 6; ++k) arow[lane + 64*k] = x[k] * inv;
    }
  }
}

// ---------------------------------------------------------------- K4: value aggregation (R8 exact)
__global__ __launch_bounds__(256) void k_agg(
    const float* __restrict__ attn, const float* __restrict__ pair,
    const float* __restrict__ rv, float* __restrict__ o_ihd, float* __restrict__ top)
{
  const int t = threadIdx.x;
  const int bi = blockIdx.x;                 // b*R + i
  const int b = bi / Rr;
  const int i = bi - b*Rr;
  __shared__ float a_l[12][384];
  for (int idx = t; idx < 12*384; idx += 256) {
    int h = idx / 384, j = idx - h*384;
    a_l[h][j] = attn[(((long)b*Hh + h)*Rr + i)*Rr + j];
  }
  __syncthreads();
  const int c = t & 127, hh = t >> 7;        // hh in {0,1}; h = hh + 2m
  const float* prow = pair + (long)bi * Rr * CZ;
  float acc0=0,acc1=0,acc2=0,acc3=0,acc4=0,acc5=0;
  for (int j = 0; j < 384; ++j) {
    float v = prow[(long)j*CZ + c];
    acc0 += a_l[hh   ][j]*v;
    acc1 += a_l[hh+2 ][j]*v;
    acc2 += a_l[hh+4 ][j]*v;
    acc3 += a_l[hh+6 ][j]*v;
    acc4 += a_l[hh+8 ][j]*v;
    acc5 += a_l[hh+10][j]*v;
  }
  float* tp = top + ((long)bi*Hh)*CZ + c;
  tp[(long)(hh   )*CZ] = acc0;
  tp[(long)(hh+2 )*CZ] = acc1;
  tp[(long)(hh+4 )*CZ] = acc2;
  tp[(long)(hh+6 )*CZ] = acc3;
  tp[(long)(hh+8 )*CZ] = acc4;
  tp[(long)(hh+10)*CZ] = acc5;
  for (int o = t; o < 384; o += 256) {
    int h = o >> 5, dd = o & 31;
    const float* rvp = rv + ((long)b*Hh + h)*Rr*DHd + dd;
    float s = 0.f;
    for (int j = 0; j < 384; ++j) s += a_l[h][j] * rvp[(long)j*DHd];
    o_ihd[(long)bi*384 + o] = s;
  }
}

// ---------------------------------------------------------------- K5: output GEMM (R8 exact)
#define K5_KSPLIT 6
#define K5_KLEN   320
__global__ __launch_bounds__(64) void k_final_part(
    const float* __restrict__ o_ihd, const float* __restrict__ top,
    const float* __restrict__ W0, const float* __restrict__ W1,
    float* __restrict__ partial)
{
  const int t = threadIdx.x;
  const int m0 = blockIdx.x * 32;
  const int n0 = blockIdx.y * 32;
  const int ks = blockIdx.z;
  const int tx = t & 7, ty = t >> 3;
  __shared__ float As[32][36];
  __shared__ float Bs[32][36];
  float acc[4][4] = {};

  for (int kc = ks*K5_KLEN; kc < ks*K5_KLEN + K5_KLEN; kc += 32) {
    #pragma unroll
    for (int i = 0; i < 4; ++i) {
      int s = t + 64*i;
      int row = s >> 3, k4 = (s & 7) << 2;
      int gk = kc + k4;
      const float* srcA = (gk < 384)
          ? o_ihd + (long)(m0 + row)*384 + gk
          : top   + (long)(m0 + row)*1536 + (gk - 384);
      float4 v = *(const float4*)srcA;
      As[k4  ][row] = v.x; As[k4+1][row] = v.y;
      As[k4+2][row] = v.z; As[k4+3][row] = v.w;
    }
    #pragma unroll
    for (int i = 0; i < 4; ++i) {
      int s = t + 64*i;
      int k = s >> 3, c4 = (s & 7) << 2;
      int gk = kc + k;
      const float* srcB = (gk < 384)
          ? W0 + (long)gk*384 + n0 + c4
          : W1 + (long)(gk - 384)*384 + n0 + c4;
      float4 w = *(const float4*)srcB;
      Bs[k][c4] = w.x; Bs[k][c4+1] = w.y; Bs[k][c4+2] = w.z; Bs[k][c4+3] = w.w;
    }
    __syncthreads();
    #pragma unroll
    for (int k = 0; k < 32; ++k) {
      float4 a = *(const float4*)&As[k][ty*4];
      float4 b = *(const float4*)&Bs[k][tx*4];
      acc[0][0] += a.x*b.x; acc[0][1] += a.x*b.y; acc[0][2] += a.x*b.z; acc[0][3] += a.x*b.w;
      acc[1][0] += a.y*b.x; acc[1][1] += a.y*b.y; acc[1][2] += a.y*b.z; acc[1][3] += a.y*b.w;
      acc[2][0] += a.z*b.x; acc[2][1] += a.z*b.y; acc[2][2] += a.z*b.z; acc[2][3] += a.z*b.w;
      acc[3][0] += a.w*b.x; acc[3][1] += a.w*b.y; acc[3][2] += a.w*b.z; acc[3][3] += a.w*b.w;
    }
    __syncthreads();
  }
  float* pdst = partial + (long)ks * (768*384);
  #pragma unroll
  for (int i = 0; i < 4; ++i)
    *(float4*)&pdst[(long)(m0 + ty*4 + i)*384 + n0 + tx*4] =
        make_float4(acc[i][0], acc[i][1], acc[i][2], acc[i][3]);
}

__global__ __launch_bounds__(256) void k_final_reduce(
    const float* __restrict__ partial, float* __restrict__ out)
{
  const int idx = blockIdx.x*256 + threadIdx.x;   // over 73728 float4
  float4 r = make_float4(0.f, 0.f, 0.f, 0.f);
  #pragma unroll
  for (int p = 0; p < K5_KSPLIT; ++p) {
    float4 a = ((const float4*)(partial + (long)p*768*384))[idx];
    r.x += a.x; r.y += a.y; r.z += a.z; r.w += a.w;
  }
  ((float4*)out)[idx] = r;
}

// ---------------------------------------------------------------- launch
extern "C" void kernel_launch(void* const* d_in, const int* in_sizes, int n_in,
                              void* d_out, int out_size, void* d_ws, size_t ws_size,
                              hipStream_t stream)
{
  (void)in_sizes; (void)n_in; (void)out_size; (void)ws_size;
  const float* pair  = (const float*)d_in[0];
  const float* sing  = (const float*)d_in[1];
  const float* bbr   = (const float*)d_in[2];
  const float* bbt   = (const float*)d_in[3];
  const float* Wqkv  = (const float*)d_in[4];
  const float* Wqk   = (const float*)d_in[5];
  const float* Wfc1  = (const float*)d_in[6];
  const float* bfc1  = (const float*)d_in[7];
  const float* W0    = (const float*)d_in[8];
  const float* W1    = (const float*)d_in[9];
  const float* gamma = (const float*)d_in[10];
  float* out = (float*)d_out;

  float* ws    = (float*)d_ws;
  float* rq    = ws;
  float* rk    = rq  + SZ_R;
  float* rv    = rk  + SZ_R;
  float* TqF   = rv  + SZ_R;
  float* TkF   = TqF + SZ_T;
  float* Qsq   = TkF + SZ_T;
  float* Ksq   = Qsq + SZ_S;
  float* attn  = Ksq + SZ_S;
  float* o_ihd = attn + SZ_A;
  float* top   = o_ihd + SZ_O;
  float* gbuf  = o_ihd;     // alias: consumed by k_frame before k_agg writes o_ihd
  float* pbuf  = attn;      // alias: 2*768*1440 < SZ_A; dead before k_pscore
  float* partial = attn;    // alias: attn dead after k_agg; 6*294912 < SZ_A

  k_projgemm<<<dim3(24, 45, 2), dim3(64), 0, stream>>>(sing, Wqkv, Wqk, pbuf);
  k_scatter<<<dim3(276480/256), dim3(256), 0, stream>>>(pbuf, rq, rk, rv, gbuf);
  k_frame<<<dim3(Bb*Rr*24/256), dim3(256), 0, stream>>>(
      gbuf, bbr, bbt, TqF, TkF, Qsq, Ksq);
  k_pscore<<<dim3(Bb*Rr), dim3(256), 0, stream>>>(
      pair, Wfc1, bfc1, rq, rk, TqF, TkF, Qsq, Ksq, gamma, attn);
  k_agg<<<dim3(Bb*Rr), dim3(256), 0, stream>>>(attn, pair, rv, o_ihd, top);
  k_final_part<<<dim3(24, 12, K5_KSPLIT), dim3(64), 0, stream>>>(
      o_ihd, top, W0, W1, partial);
  k_final_reduce<<<dim3(768*384/4/256), dim3(256), 0, stream>>>(partial, out);
}

// Round 20
// 191.931 us; speedup vs baseline: 1.1702x; 1.1702x over previous
//
#include <hip/hip_runtime.h>
#include <math.h>

#define Bb   2
#define Rr   384
#define CMd  384
#define CZ   128
#define Hh   12
#define DHd  32

#define WL           1.7320508075688772f   // sqrt(3)
#define WC           4.242640687119285f    // sqrt(18) = (2/(9*4))^-0.5
#define INV_SQRT_DH  0.17677669529663687f  // 32^-0.5

#define SZ_R   (Bb*Hh*Rr*DHd)      // 294912
#define SZ_T   (Bb*Hh*Rr*12)      // 110592
#define SZ_S   (Bb*Hh*Rr)         // 9216
#define SZ_A   ((long)Bb*Hh*Rr*Rr) // 3538944
#define SZ_O   (Bb*Rr*Hh*DHd)     // 294912

// ---------------------------------------------------------------- K1a: projection GEMM (R8 exact)
__global__ __launch_bounds__(64) void k_projgemm(
    const float* __restrict__ sing, const float* __restrict__ Wqkv,
    const float* __restrict__ Wqk, float* __restrict__ pbuf)
{
  const int t = threadIdx.x;
  const int m0 = blockIdx.x * 32;
  const int n0 = blockIdx.y * 32;
  const int ks = blockIdx.z;
  const int tx = t & 7, ty = t >> 3;
  __shared__ float As[32][36];
  __shared__ float Bs[32][36];
  float acc[4][4] = {};

  for (int kc = ks*192; kc < ks*192 + 192; kc += 32) {
    #pragma unroll
    for (int i = 0; i < 4; ++i) {
      int s = t + 64*i;
      int row = s >> 3, k4 = (s & 7) << 2;
      float4 v = *(const float4*)(sing + (long)(m0 + row)*384 + kc + k4);
      As[k4  ][row] = v.x; As[k4+1][row] = v.y;
      As[k4+2][row] = v.z; As[k4+3][row] = v.w;
    }
    #pragma unroll
    for (int i = 0; i < 4; ++i) {
      int s = t + 64*i;
      int k = s >> 3, c4 = (s & 7) << 2;
      const float* srcB = (n0 < 1152)
          ? Wqkv + (long)(kc + k)*1152 + n0 + c4
          : Wqk  + (long)(kc + k)*288 + (n0 - 1152) + c4;
      float4 w = *(const float4*)srcB;
      Bs[k][c4] = w.x; Bs[k][c4+1] = w.y; Bs[k][c4+2] = w.z; Bs[k][c4+3] = w.w;
    }
    __syncthreads();
    #pragma unroll
    for (int k = 0; k < 32; ++k) {
      float4 a = *(const float4*)&As[k][ty*4];
      float4 b = *(const float4*)&Bs[k][tx*4];
      acc[0][0] += a.x*b.x; acc[0][1] += a.x*b.y; acc[0][2] += a.x*b.z; acc[0][3] += a.x*b.w;
      acc[1][0] += a.y*b.x; acc[1][1] += a.y*b.y; acc[1][2] += a.y*b.z; acc[1][3] += a.y*b.w;
      acc[2][0] += a.z*b.x; acc[2][1] += a.z*b.y; acc[2][2] += a.z*b.z; acc[2][3] += a.z*b.w;
      acc[3][0] += a.w*b.x; acc[3][1] += a.w*b.y; acc[3][2] += a.w*b.z; acc[3][3] += a.w*b.w;
    }
    __syncthreads();
  }
  float* pd = pbuf + (long)ks * (768*1440);
  #pragma unroll
  for (int i = 0; i < 4; ++i)
    *(float4*)&pd[(long)(m0 + ty*4 + i)*1440 + n0 + tx*4] =
        make_float4(acc[i][0], acc[i][1], acc[i][2], acc[i][3]);
}

// ---------------------------------------------------------------- K1a2: reduce partials + scatter (R8 exact)
__global__ __launch_bounds__(256) void k_scatter(
    const float* __restrict__ pbuf,
    float* __restrict__ rq, float* __restrict__ rk, float* __restrict__ rv,
    float* __restrict__ gbuf)
{
  const int idx = blockIdx.x*256 + threadIdx.x;   // over 276480 float4
  const int row = idx / 360;
  const int n   = (idx - row*360) * 4;
  float4 a = ((const float4*)pbuf)[idx];
  float4 b = ((const float4*)(pbuf + (long)768*1440))[idx];
  float v[4] = {a.x + b.x, a.y + b.y, a.z + b.z, a.w + b.w};
  const int bb = row / Rr, rr = row - bb*Rr;
  #pragma unroll
  for (int j = 0; j < 4; ++j) {
    int nj = n + j;
    if (nj < 1152) {
      int d = nj/36, rem = nj - d*36, wh = rem/12, h = rem - wh*12;
      float* dst = (wh == 0) ? rq : (wh == 1) ? rk : rv;
      dst[(((long)bb*Hh + h)*Rr + rr)*DHd + d] = v[j];
    } else {
      gbuf[(long)row*288 + nj - 1152] = v[j];
    }
  }
}

// ---------------------------------------------------------------- K1b: frame transform (R8 exact)
__global__ __launch_bounds__(256) void k_frame(
    const float* __restrict__ gbuf, const float* __restrict__ bbr,
    const float* __restrict__ bbt,
    float* __restrict__ TqF, float* __restrict__ TkF,
    float* __restrict__ Qsq, float* __restrict__ Ksq)
{
  const int idx = blockIdx.x*256 + threadIdx.x;   // 768*24 exact
  const int row = idx / 24, q = idx - row*24;
  const int h = q >> 1, s2 = q & 1;
  const float* gp = gbuf + (long)row*288 + h*24 + s2*12;
  float rot[9], tr[3];
  #pragma unroll
  for (int a = 0; a < 9; ++a) rot[a] = bbr[(long)row*9 + a];
  #pragma unroll
  for (int a = 0; a < 3; ++a) tr[a] = bbt[(long)row*3 + a];
  const int b = row / Rr, r = row - b*Rr;
  float* T = s2 ? TkF : TqF;
  const long tb = (((long)b*Hh + h)*Rr + r)*12;
  float v[12]; float ss = 0.f;
  #pragma unroll
  for (int p = 0; p < 4; ++p)
    #pragma unroll
    for (int k2 = 0; k2 < 3; ++k2) {
      float x = gp[p*3+0]*rot[k2] + gp[p*3+1]*rot[3+k2] + gp[p*3+2]*rot[6+k2] + tr[k2];
      v[p*3+k2] = x; ss += x*x;
    }
  *(float4*)(T + tb)     = make_float4(v[0], v[1], v[2],  v[3]);
  *(float4*)(T + tb + 4) = make_float4(v[4], v[5], v[6],  v[7]);
  *(float4*)(T + tb + 8) = make_float4(v[8], v[9], v[10], v[11]);
  (s2 ? Ksq : Qsq)[((long)b*Hh + h)*Rr + r] = ss;
}

// ---------------------------------------------------------------- K2: pair bias (R15 exact)
__global__ __launch_bounds__(256) void k_pbias(
    const float* __restrict__ pair, const float* __restrict__ Wfc1,
    const float* __restrict__ bfc1, float* __restrict__ pb)
{
  const int t = threadIdx.x;
  const int su = t & 7, rg = t >> 3;            // rg in [0,32)
  __shared__ __align__(16) float w_t[12*128];   // w_t[h][c]
  __shared__ float bias_l[12];
  for (int s = t; s < 1536; s += 256) {
    int h = s >> 7, c = s & 127;
    w_t[s] = Wfc1[c*12 + h];
  }
  if (t < 12) bias_l[t] = bfc1[t];
  __syncthreads();

  const long rbase = (long)blockIdx.x * 128;    // 128 consecutive rows; never crosses b
  const float4* pr = (const float4*)pair;
  float acc[4][12] = {};
  #pragma unroll
  for (int cc = 0; cc < 4; ++cc) {
    const int f = su + 8*cc;                    // float4 index within row
    float4 p0 = pr[(rbase + rg      )*32 + f];
    float4 p1 = pr[(rbase + rg + 32 )*32 + f];
    float4 p2 = pr[(rbase + rg + 64 )*32 + f];
    float4 p3 = pr[(rbase + rg + 96 )*32 + f];
    #pragma unroll
    for (int h = 0; h < 12; ++h) {
      float4 wv = *(const float4*)&w_t[h*128 + f*4];
      acc[0][h] += p0.x*wv.x + p0.y*wv.y + p0.z*wv.z + p0.w*wv.w;
      acc[1][h] += p1.x*wv.x + p1.y*wv.y + p1.z*wv.z + p1.w*wv.w;
      acc[2][h] += p2.x*wv.x + p2.y*wv.y + p2.z*wv.z + p2.w*wv.w;
      acc[3][h] += p3.x*wv.x + p3.y*wv.y + p3.z*wv.z + p3.w*wv.w;
    }
  }
  #pragma unroll
  for (int rr = 0; rr < 4; ++rr)
    #pragma unroll
    for (int h = 0; h < 12; ++h) {
      float v = acc[rr][h];
      v += __shfl_xor(v, 1, 64);
      v += __shfl_xor(v, 2, 64);
      v += __shfl_xor(v, 4, 64);
      acc[rr][h] = v;
    }
  if (su == 0) {
    const int b0 = (int)(rbase / 147456);
    const long ro = rbase - (long)b0*147456;
    #pragma unroll
    for (int rr = 0; rr < 4; ++rr) {
      const long jrow = ro + rg + 32*rr;
      #pragma unroll
      for (int h = 0; h < 12; ++h)
        pb[((long)b0*Hh + h)*147456 + jrow] = acc[rr][h] + bias_l[h];
    }
  }
}

// ---------------------------------------------------------------- K3: scores + softmax (R17 exact)
#define ITILE 8
__global__ __launch_bounds__(256) void k_scores(
    const float* __restrict__ rq, const float* __restrict__ rk,
    const float* __restrict__ TqF, const float* __restrict__ TkF,
    const float* __restrict__ Qsq, const float* __restrict__ Ksq,
    const float* __restrict__ gamma, float* __restrict__ attn)
{
  const int t = threadIdx.x;
  const int nt = Rr / ITILE;                 // 48
  const int bh = blockIdx.x / nt;
  const int i0 = (blockIdx.x - bh*nt) * ITILE;
  __shared__ __align__(16) float rkf[384*32];   // 48 KB, quad-swizzled
  __shared__ __align__(16) float rq_l[32];
  __shared__ float tq_l[12];
  __shared__ float scal[1];
  __shared__ float redm[4], reds[4];

  for (int idx = t; idx < 384*32; idx += 256) {
    int j = idx >> 5, dd = idx & 31;
    int q = dd >> 2, e = dd & 3;
    rkf[(j << 5) + (((q ^ (j & 7)) << 2) | e)] = rk[(long)bh*Rr*DHd + idx];
  }

  const float g0 = gamma[0];
  const float head_w = log1pf(__expf(g0)) * (WC * 0.5f);

  for (int ii = 0; ii < ITILE; ++ii) {
    const int i = i0 + ii;
    if (t < 32) rq_l[t] = rq[((long)bh*Rr + i)*DHd + t];
    if (t < 12) tq_l[t] = TqF[((long)bh*Rr + i)*12 + t];
    if (t == 0) scal[0] = Qsq[(long)bh*Rr + i];
    __syncthreads();
    const float qs = scal[0];
    const long rowbase = ((long)bh*Rr + i)*Rr;

    auto logit_at = [&](int j) -> float {
      const float* rkrow = &rkf[j << 5];
      const int sw = j & 7;
      float dt = 0.f;
      #pragma unroll
      for (int q = 0; q < 8; ++q) {
        float4 kv = *(const float4*)&rkrow[(q ^ sw) << 2];
        float4 qv = *(const float4*)&rq_l[q << 2];
        dt += kv.x*qv.x + kv.y*qv.y + kv.z*qv.z + kv.w*qv.w;
      }
      const float4* tk = (const float4*)(TkF + ((long)bh*Rr + j)*12);
      float4 ta = tk[0], tb = tk[1], tc = tk[2];
      float pt = tq_l[0]*ta.x + tq_l[1]*ta.y + tq_l[2]*ta.z + tq_l[3]*ta.w
               + tq_l[4]*tb.x + tq_l[5]*tb.y + tq_l[6]*tb.z + tq_l[7]*tb.w
               + tq_l[8]*tc.x + tq_l[9]*tc.y + tq_l[10]*tc.z + tq_l[11]*tc.w;
      float sqv = qs + Ksq[(long)bh*Rr + j] - 2.f*pt;
      return WL * (attn[rowbase + j] + dt*INV_SQRT_DH + head_w*sqv);
    };

    float l0 = logit_at(t);
    float l1 = (t < 128) ? logit_at(t + 256) : -3.4e38f;
    float m = fmaxf(l0, l1);
    #pragma unroll
    for (int s = 32; s; s >>= 1) m = fmaxf(m, __shfl_xor(m, s, 64));
    if ((t & 63) == 0) redm[t >> 6] = m;
    __syncthreads();
    m = fmaxf(fmaxf(redm[0], redm[1]), fmaxf(redm[2], redm[3]));
    float e0 = __expf(l0 - m);
    float e1 = (t < 128) ? __expf(l1 - m) : 0.f;
    float s = e0 + e1;
    #pragma unroll
    for (int sh = 32; sh; sh >>= 1) s += __shfl_xor(s, sh, 64);
    if ((t & 63) == 0) reds[t >> 6] = s;
    __syncthreads();
    float inv = 1.f / (reds[0] + reds[1] + reds[2] + reds[3]);
    attn[rowbase + t] = e0 * inv;
    if (t < 128) attn[rowbase + t + 256] = e1 * inv;
    __syncthreads();
  }
}

// ---------------------------------------------------------------- K4: value aggregation (R8 exact)
__global__ __launch_bounds__(256) void k_agg(
    const float* __restrict__ attn, const float* __restrict__ pair,
    const float* __restrict__ rv, float* __restrict__ o_ihd, float* __restrict__ top)
{
  const int t = threadIdx.x;
  const int bi = blockIdx.x;                 // b*R + i
  const int b = bi / Rr;
  const int i = bi - b*Rr;
  __shared__ float a_l[12][384];
  for (int idx = t; idx < 12*384; idx += 256) {
    int h = idx / 384, j = idx - h*384;
    a_l[h][j] = attn[(((long)b*Hh + h)*Rr + i)*Rr + j];
  }
  __syncthreads();
  const int c = t & 127, hh = t >> 7;        // hh in {0,1}; h = hh + 2m
  const float* prow = pair + (long)bi * Rr * CZ;
  float acc0=0,acc1=0,acc2=0,acc3=0,acc4=0,acc5=0;
  for (int j = 0; j < 384; ++j) {
    float v = prow[(long)j*CZ + c];
    acc0 += a_l[hh   ][j]*v;
    acc1 += a_l[hh+2 ][j]*v;
    acc2 += a_l[hh+4 ][j]*v;
    acc3 += a_l[hh+6 ][j]*v;
    acc4 += a_l[hh+8 ][j]*v;
    acc5 += a_l[hh+10][j]*v;
  }
  float* tp = top + ((long)bi*Hh)*CZ + c;
  tp[(long)(hh   )*CZ] = acc0;
  tp[(long)(hh+2 )*CZ] = acc1;
  tp[(long)(hh+4 )*CZ] = acc2;
  tp[(long)(hh+6 )*CZ] = acc3;
  tp[(long)(hh+8 )*CZ] = acc4;
  tp[(long)(hh+10)*CZ] = acc5;
  for (int o = t; o < 384; o += 256) {
    int h = o >> 5, dd = o & 31;
    const float* rvp = rv + ((long)b*Hh + h)*Rr*DHd + dd;
    float s = 0.f;
    for (int j = 0; j < 384; ++j) s += a_l[h][j] * rvp[(long)j*DHd];
    o_ihd[(long)bi*384 + o] = s;
  }
}

// ---------------------------------------------------------------- K5: output GEMM (R8 exact)
#define K5_KSPLIT 6
#define K5_KLEN   320
__global__ __launch_bounds__(64) void k_final_part(
    const float* __restrict__ o_ihd, const float* __restrict__ top,
    const float* __restrict__ W0, const float* __restrict__ W1,
    float* __restrict__ partial)
{
  const int t = threadIdx.x;
  const int m0 = blockIdx.x * 32;
  const int n0 = blockIdx.y * 32;
  const int ks = blockIdx.z;
  const int tx = t & 7, ty = t >> 3;
  __shared__ float As[32][36];
  __shared__ float Bs[32][36];
  float acc[4][4] = {};

  for (int kc = ks*K5_KLEN; kc < ks*K5_KLEN + K5_KLEN; kc += 32) {
    #pragma unroll
    for (int i = 0; i < 4; ++i) {
      int s = t + 64*i;
      int row = s >> 3, k4 = (s & 7) << 2;
      int gk = kc + k4;
      const float* srcA = (gk < 384)
          ? o_ihd + (long)(m0 + row)*384 + gk
          : top   + (long)(m0 + row)*1536 + (gk - 384);
      float4 v = *(const float4*)srcA;
      As[k4  ][row] = v.x; As[k4+1][row] = v.y;
      As[k4+2][row] = v.z; As[k4+3][row] = v.w;
    }
    #pragma unroll
    for (int i = 0; i < 4; ++i) {
      int s = t + 64*i;
      int k = s >> 3, c4 = (s & 7) << 2;
      int gk = kc + k;
      const float* srcB = (gk < 384)
          ? W0 + (long)gk*384 + n0 + c4
          : W1 + (long)(gk - 384)*384 + n0 + c4;
      float4 w = *(const float4*)srcB;
      Bs[k][c4] = w.x; Bs[k][c4+1] = w.y; Bs[k][c4+2] = w.z; Bs[k][c4+3] = w.w;
    }
    __syncthreads();
    #pragma unroll
    for (int k = 0; k < 32; ++k) {
      float4 a = *(const float4*)&As[k][ty*4];
      float4 b = *(const float4*)&Bs[k][tx*4];
      acc[0][0] += a.x*b.x; acc[0][1] += a.x*b.y; acc[0][2] += a.x*b.z; acc[0][3] += a.x*b.w;
      acc[1][0] += a.y*b.x; acc[1][1] += a.y*b.y; acc[1][2] += a.y*b.z; acc[1][3] += a.y*b.w;
      acc[2][0] += a.z*b.x; acc[2][1] += a.z*b.y; acc[2][2] += a.z*b.z; acc[2][3] += a.z*b.w;
      acc[3][0] += a.w*b.x; acc[3][1] += a.w*b.y; acc[3][2] += a.w*b.z; acc[3][3] += a.w*b.w;
    }
    __syncthreads();
  }
  float* pdst = partial + (long)ks * (768*384);
  #pragma unroll
  for (int i = 0; i < 4; ++i)
    *(float4*)&pdst[(long)(m0 + ty*4 + i)*384 + n0 + tx*4] =
        make_float4(acc[i][0], acc[i][1], acc[i][2], acc[i][3]);
}

__global__ __launch_bounds__(256) void k_final_reduce(
    const float* __restrict__ partial, float* __restrict__ out)
{
  const int idx = blockIdx.x*256 + threadIdx.x;   // over 73728 float4
  float4 r = make_float4(0.f, 0.f, 0.f, 0.f);
  #pragma unroll
  for (int p = 0; p < K5_KSPLIT; ++p) {
    float4 a = ((const float4*)(partial + (long)p*768*384))[idx];
    r.x += a.x; r.y += a.y; r.z += a.z; r.w += a.w;
  }
  ((float4*)out)[idx] = r;
}

// ---------------------------------------------------------------- launch
extern "C" void kernel_launch(void* const* d_in, const int* in_sizes, int n_in,
                              void* d_out, int out_size, void* d_ws, size_t ws_size,
                              hipStream_t stream)
{
  (void)in_sizes; (void)n_in; (void)out_size; (void)ws_size;
  const float* pair  = (const float*)d_in[0];
  const float* sing  = (const float*)d_in[1];
  const float* bbr   = (const float*)d_in[2];
  const float* bbt   = (const float*)d_in[3];
  const float* Wqkv  = (const float*)d_in[4];
  const float* Wqk   = (const float*)d_in[5];
  const float* Wfc1  = (const float*)d_in[6];
  const float* bfc1  = (const float*)d_in[7];
  const float* W0    = (const float*)d_in[8];
  const float* W1    = (const float*)d_in[9];
  const float* gamma = (const float*)d_in[10];
  float* out = (float*)d_out;

  float* ws    = (float*)d_ws;
  float* rq    = ws;
  float* rk    = rq  + SZ_R;
  float* rv    = rk  + SZ_R;
  float* TqF   = rv  + SZ_R;
  float* TkF   = TqF + SZ_T;
  float* Qsq   = TkF + SZ_T;
  float* Ksq   = Qsq + SZ_S;
  float* attn  = Ksq + SZ_S;
  float* o_ihd = attn + SZ_A;
  float* top   = o_ihd + SZ_O;
  float* gbuf  = o_ihd;     // alias: consumed by k_frame before k_agg writes o_ihd
  float* pbuf  = attn;      // alias: 2*768*1440 < SZ_A; dead before k_pbias
  float* partial = attn;    // alias: attn dead after k_agg; 6*294912 < SZ_A

  k_projgemm<<<dim3(24, 45, 2), dim3(64), 0, stream>>>(sing, Wqkv, Wqk, pbuf);
  k_scatter<<<dim3(276480/256), dim3(256), 0, stream>>>(pbuf, rq, rk, rv, gbuf);
  k_frame<<<dim3(Bb*Rr*24/256), dim3(256), 0, stream>>>(
      gbuf, bbr, bbt, TqF, TkF, Qsq, Ksq);
  k_pbias<<<dim3(Bb*Rr*Rr/128), dim3(256), 0, stream>>>(pair, Wfc1, bfc1, attn);
  k_scores<<<dim3(Bb*Hh*(Rr/ITILE)), dim3(256), 0, stream>>>(
      rq, rk, TqF, TkF, Qsq, Ksq, gamma, attn);
  k_agg<<<dim3(Bb*Rr), dim3(256), 0, stream>>>(attn, pair, rv, o_ihd, top);
  k_final_part<<<dim3(24, 12, K5_KSPLIT), dim3(64), 0, stream>>>(
      o_ihd, top, W0, W1, partial);
  k_final_reduce<<<dim3(768*384/4/256), dim3(256), 0, stream>>>(partial, out);
}